// Round 14
// baseline (206.791 us; speedup 1.0000x reference)
//
#include <hip/hip_runtime.h>

// DeltaModulationEncoder: x (16, 256, 8192) f32 -> spikes {-1,0,1} f32.
// Exact monolithic scan (recurrence serial per channel).
//
// Calibrated model (R12: 5.5 hops -> 62 cyc/step; R13: 5 hops -> 55):
// dependent VALU latency L ~= 11 cyc at 1 wave/SIMD; memory fully hidden by
// the hand-asm 16-deep pipeline (loads 16 slots ahead, exact vmcnt(30),
// rotating spike register sets). Wall = hops x L. This round: 4-hop step
// (floor for select-based exact semantics):
//   stub:  rp = fl(r+th), rm = fl(r-th)     (off-chain, 1 hop from r)
//   hop1:  d  = x - r                       (v_sub)
//   hop2:  c1 = (th < d)  -> s[12:13]       (VOP3 cmp; PARALLEL with c2 --
//          c2 = (-th > d) -> s[14:15]        different SGPR dests, no vcc WAR)
//   hop3:  r = c1 ? rp : r                  (cndmask, sgpr-pair mask)
//   hop4:  r = c2 ? rm : r
//   off:   spike = c2 ? -1 : (c1 ? 1 : 0)   (2 cndmasks, inline consts)
// Bit-exact vs reference: strict compares on err itself; rp/rm are exactly
// the reference's recon + net*th values (net*th = +-0.1f exact); c1,c2
// mutually exclusive; net==0 keeps r (recon never -0.0f). No mul feeds an
// add. NaN impossible (finite inputs); both cmps false -> net 0 like ref.
//
// Register map (fixed, compiler never touches):
//   v33 recon | v40 byte-voffset | v48,v49,v50 step temps
//   v[64+4j..67+4j]   q[j]  16-deep load pipeline (j=0..15)
//   v[128+4j..131+4j] spike set j (rotating: store-source regs overwritten
//                     only after vmcnt proves the store retired)
//   s8=+0.1f, s9=-0.1f, s[12:13]/s[14:15] step condition masks.
// Per slot: s_waitcnt vmcnt(30) [exact: my load and this spike-set's previous
// store are both 31 ops old], 4 steps, store(chunk), load(chunk+16).
// 256 blocks x 1 wave; lanes 0-15 each own one channel (4096 total).

constexpr int T    = 8192;
constexpr int NCH  = 4096;
constexpr int CPB  = 16;
constexpr int NBLK = NCH / CPB;   // 256

#define STEP(X,S) \
  "v_add_f32 v49, s8, v33\n\t"                  /* rp = th + r    (stub) */ \
  "v_subrev_f32 v50, s8, v33\n\t"               /* rm = r - th    (stub) */ \
  "v_sub_f32 v48, v" #X ", v33\n\t"             /* d = x - r       hop1 */ \
  "v_cmp_lt_f32_e64 s[12:13], s8, v48\n\t"      /* c1: th < d      hop2 */ \
  "v_cmp_gt_f32_e64 s[14:15], s9, v48\n\t"      /* c2: -th > d     hop2 */ \
  "v_cndmask_b32 v33, v33, v49, s[12:13]\n\t"   /* r = c1?rp:r     hop3 */ \
  "v_cndmask_b32 v33, v33, v50, s[14:15]\n\t"   /* r = c2?rm:r     hop4 */ \
  "v_cndmask_b32 v" #S ", 0, 1.0, s[12:13]\n\t"        /* sp = c1?1:0  off */ \
  "v_cndmask_b32 v" #S ", v" #S ", -1.0, s[14:15]\n\t" /* sp = c2?-1:sp off */

#define SLOT_CLOB(Q0,Q1,Q2,Q3,P0,P1,P2,P3) \
  "memory","s8","s9","s12","s13","s14","s15", \
  "v33","v48","v49","v50", \
  "v" #Q0,"v" #Q1,"v" #Q2,"v" #Q3,"v" #P0,"v" #P1,"v" #P2,"v" #P3

// Steady-state slot: wait(exact) + 4 steps + store(chunk) + load(chunk+16).
#define SLOT(Q0,Q1,Q2,Q3,P0,P1,P2,P3,OFFS,OFFL) asm volatile( \
  "s_waitcnt vmcnt(30)\n\t" \
  STEP(Q0,P0) STEP(Q1,P1) STEP(Q2,P2) STEP(Q3,P3) \
  "global_store_dwordx4 v40, v[" #P0 ":" #P3 "], %1 offset:" #OFFS "\n\t" \
  "global_load_dwordx4 v[" #Q0 ":" #Q3 "], v40, %0 offset:" #OFFL "\n\t" \
  :: "s"(xp), "s"(op) : SLOT_CLOB(Q0,Q1,Q2,Q3,P0,P1,P2,P3))

// Final-iteration slot: everything drained beforehand; no wait, no load.
#define SLOTND(Q0,Q1,Q2,Q3,P0,P1,P2,P3,OFFS) asm volatile( \
  STEP(Q0,P0) STEP(Q1,P1) STEP(Q2,P2) STEP(Q3,P3) \
  "global_store_dwordx4 v40, v[" #P0 ":" #P3 "], %1 offset:" #OFFS "\n\t" \
  :: "s"(xp), "s"(op) : SLOT_CLOB(Q0,Q1,Q2,Q3,P0,P1,P2,P3))

__global__ __launch_bounds__(64, 1) void dm_scan(const float* __restrict__ x,
                                                 float* __restrict__ out) {
    const int lane = threadIdx.x;
    if (lane >= CPB) return;                  // exec = 0xFFFF for the rest
    const int ch = blockIdx.x * CPB + lane;

    const float* xp = x;                      // uniform -> "s" (SADDR base)
    float*       op = out;
    unsigned off0 = (unsigned)ch * (unsigned)(T * 4);   // per-lane byte offset

    // Prologue: consts, recon=0, voffset, fill the 16-slot pipeline, drain.
    asm volatile(
        "s_mov_b32 s8, 0x3dcccccd\n\t"        // +0.1f
        "s_mov_b32 s9, 0xbdcccccd\n\t"        // -0.1f
        "v_mov_b32 v33, 0\n\t"
        "v_mov_b32 v40, %2\n\t"
        "global_load_dwordx4 v[64:67],   v40, %0\n\t"
        "global_load_dwordx4 v[68:71],   v40, %0 offset:16\n\t"
        "global_load_dwordx4 v[72:75],   v40, %0 offset:32\n\t"
        "global_load_dwordx4 v[76:79],   v40, %0 offset:48\n\t"
        "global_load_dwordx4 v[80:83],   v40, %0 offset:64\n\t"
        "global_load_dwordx4 v[84:87],   v40, %0 offset:80\n\t"
        "global_load_dwordx4 v[88:91],   v40, %0 offset:96\n\t"
        "global_load_dwordx4 v[92:95],   v40, %0 offset:112\n\t"
        "global_load_dwordx4 v[96:99],   v40, %0 offset:128\n\t"
        "global_load_dwordx4 v[100:103], v40, %0 offset:144\n\t"
        "global_load_dwordx4 v[104:107], v40, %0 offset:160\n\t"
        "global_load_dwordx4 v[108:111], v40, %0 offset:176\n\t"
        "global_load_dwordx4 v[112:115], v40, %0 offset:192\n\t"
        "global_load_dwordx4 v[116:119], v40, %0 offset:208\n\t"
        "global_load_dwordx4 v[120:123], v40, %0 offset:224\n\t"
        "global_load_dwordx4 v[124:127], v40, %0 offset:240\n\t"
        "s_waitcnt vmcnt(0)\n\t"
        :: "s"(xp), "s"(op), "v"(off0)
        : "memory","s8","s9","s12","s13","s14","s15",
          "v33","v40","v48","v49","v50",
          "v64","v65","v66","v67","v68","v69","v70","v71",
          "v72","v73","v74","v75","v76","v77","v78","v79",
          "v80","v81","v82","v83","v84","v85","v86","v87",
          "v88","v89","v90","v91","v92","v93","v94","v95",
          "v96","v97","v98","v99","v100","v101","v102","v103",
          "v104","v105","v106","v107","v108","v109","v110","v111",
          "v112","v113","v114","v115","v116","v117","v118","v119",
          "v120","v121","v122","v123","v124","v125","v126","v127");

    // 127 iterations x 16 chunks; slot j consumes chunk (16*it + j) and
    // prefetches chunk (16*it + j + 16). Last prefetch: it=126, j=15 ->
    // chunk 2047 (in bounds).
#pragma clang loop unroll(disable)
    for (int it = 0; it < 127; ++it) {
        SLOT( 64, 65, 66, 67, 128,129,130,131,   0, 256);
        SLOT( 68, 69, 70, 71, 132,133,134,135,  16, 272);
        SLOT( 72, 73, 74, 75, 136,137,138,139,  32, 288);
        SLOT( 76, 77, 78, 79, 140,141,142,143,  48, 304);
        SLOT( 80, 81, 82, 83, 144,145,146,147,  64, 320);
        SLOT( 84, 85, 86, 87, 148,149,150,151,  80, 336);
        SLOT( 88, 89, 90, 91, 152,153,154,155,  96, 352);
        SLOT( 92, 93, 94, 95, 156,157,158,159, 112, 368);
        SLOT( 96, 97, 98, 99, 160,161,162,163, 128, 384);
        SLOT(100,101,102,103, 164,165,166,167, 144, 400);
        SLOT(104,105,106,107, 168,169,170,171, 160, 416);
        SLOT(108,109,110,111, 172,173,174,175, 176, 432);
        SLOT(112,113,114,115, 176,177,178,179, 192, 448);
        SLOT(116,117,118,119, 180,181,182,183, 208, 464);
        SLOT(120,121,122,123, 184,185,186,187, 224, 480);
        SLOT(124,125,126,127, 188,189,190,191, 240, 496);
        asm volatile("v_add_u32 v40, 0x100, v40" ::: "v40");
    }

    // Final 16 chunks (2032..2047): drain once, then compute+store only.
    asm volatile("s_waitcnt vmcnt(0)" ::: "memory");
    SLOTND( 64, 65, 66, 67, 128,129,130,131,   0);
    SLOTND( 68, 69, 70, 71, 132,133,134,135,  16);
    SLOTND( 72, 73, 74, 75, 136,137,138,139,  32);
    SLOTND( 76, 77, 78, 79, 140,141,142,143,  48);
    SLOTND( 80, 81, 82, 83, 144,145,146,147,  64);
    SLOTND( 84, 85, 86, 87, 148,149,150,151,  80);
    SLOTND( 88, 89, 90, 91, 152,153,154,155,  96);
    SLOTND( 92, 93, 94, 95, 156,157,158,159, 112);
    SLOTND( 96, 97, 98, 99, 160,161,162,163, 128);
    SLOTND(100,101,102,103, 164,165,166,167, 144);
    SLOTND(104,105,106,107, 168,169,170,171, 160);
    SLOTND(108,109,110,111, 172,173,174,175, 176);
    SLOTND(112,113,114,115, 176,177,178,179, 192);
    SLOTND(116,117,118,119, 180,181,182,183, 208);
    SLOTND(120,121,122,123, 184,185,186,187, 224);
    SLOTND(124,125,126,127, 188,189,190,191, 240);
}

extern "C" void kernel_launch(void* const* d_in, const int* in_sizes, int n_in,
                              void* d_out, int out_size, void* d_ws, size_t ws_size,
                              hipStream_t stream) {
    const float* x   = (const float*)d_in[0];
    float*       out = (float*)d_out;
    dm_scan<<<NBLK, 64, 0, stream>>>(x, out);
}